// Round 11
// baseline (290.812 us; speedup 1.0000x reference)
//
#include <hip/hip_runtime.h>
#include <hip/hip_bf16.h>
#include <stdint.h>

typedef float  f32x4  __attribute__((ext_vector_type(4)));
typedef short  bf16x8 __attribute__((ext_vector_type(8)));
typedef short  bf16x4 __attribute__((ext_vector_type(4)));
typedef unsigned short u16x8 __attribute__((ext_vector_type(8)));

#define MFMA16(a, b, c) __builtin_amdgcn_mfma_f32_16x16x32_bf16((a), (b), (c), 0, 0, 0)

// 16x16x16 bf16 MFMA: A/B = 4 bf16/lane (k = (lane>>4)*4 + reg), C/D standard 16x16.
#if __has_builtin(__builtin_amdgcn_mfma_f32_16x16x16bf16_1k)
#define MFMA16K16(a, b, c) __builtin_amdgcn_mfma_f32_16x16x16bf16_1k((a), (b), (c), 0, 0, 0)
#else
__device__ __forceinline__ f32x4 mfma16k16_asm(bf16x4 a, bf16x4 b, f32x4 c) {
  f32x4 d;
  asm volatile("v_mfma_f32_16x16x16_bf16 %0, %1, %2, %3"
               : "=v"(d) : "v"(a), "v"(b), "v"(c));
  return d;
}
#define MFMA16K16(a, b, c) mfma16k16_asm((a), (b), (c))
#endif

__device__ __forceinline__ void gload16(const void* g, void* l) {
  __builtin_amdgcn_global_load_lds((const __attribute__((address_space(1))) void*)g,
                                   (__attribute__((address_space(3))) void*)l,
                                   16, 0, 0);
}

__device__ __forceinline__ unsigned short bf16bits(float f) {
  __hip_bfloat16 h = __float2bfloat16(f);
  return *(unsigned short*)&h;
}

__device__ __forceinline__ float bf2f(unsigned short u) {
  unsigned int x = ((unsigned int)u) << 16;
  return *(float*)&x;
}

// LDS-only barrier: drains DS ops, leaves VMEM (vmcnt) in flight.
__device__ __forceinline__ void block_sync_lds() {
  asm volatile("s_waitcnt lgkmcnt(0)" ::: "memory");
  __builtin_amdgcn_s_barrier();
  asm volatile("" ::: "memory");
}

// ---------------- fp32 -> bf16 cast, 4 elems/thread ----------------
__global__ void cast_kernel(const float* __restrict__ s, __hip_bfloat16* __restrict__ d, int n4) {
  int i = blockIdx.x * blockDim.x + threadIdx.x;
  if (i < n4) {
    float4 v = ((const float4*)s)[i];
    ushort4 u;
    u.x = bf16bits(v.x); u.y = bf16bits(v.y); u.z = bf16bits(v.z); u.w = bf16bits(v.w);
    ((ushort4*)d)[i] = u;
  }
}

// ---------------- GEMM1: qkv = xb @ wqkvb^T + b_qkv; scatter to Q,K',Vtile (bf16) ----------------
// V layout: Vt[bh][kb=s/16][d=64][ki=16] (r9, proven). v10 K layout:
// K'[bh][kb][dh=d/32][dq=(d/8)%4][ki=s%16][di=d%8] -- the QK A-fragment
// (lane holds K[k=lr][d=lq*8..+8]) becomes a wave-contiguous 1 KB b128 load,
// so attn needs NO K staging in LDS at all.
__global__ __launch_bounds__(256) void gemm_qkv_kernel(
    const __hip_bfloat16* __restrict__ A,
    const __hip_bfloat16* __restrict__ B,
    const float* __restrict__ bias,
    __hip_bfloat16* __restrict__ Qo,
    __hip_bfloat16* __restrict__ Ko,
    __hip_bfloat16* __restrict__ Vt) {
  const int K = 1024;
  __shared__ __align__(16) __hip_bfloat16 As[128 * 32];
  __shared__ __align__(16) __hip_bfloat16 Bs[128 * 32];
  const int t = threadIdx.x;
  const int lane = t & 63, wv = t >> 6;
  const int wm = (wv >> 1) * 64, wn = (wv & 1) * 64;
  const int lr = lane & 15, lq = lane >> 4;
  const int m0 = blockIdx.y * 128, n0 = blockIdx.x * 128;

  f32x4 acc[4][4] = {};

  const int arow = t >> 2;
  const int acol = (t & 3) * 8;
  const __hip_bfloat16* Ag = A + (long)(m0 + arow) * K + acol;
  const __hip_bfloat16* Bg = B + (long)(n0 + arow) * K + acol;
  __hip_bfloat16* Asl = As + t * 8;
  __hip_bfloat16* Bsl = Bs + t * 8;

  for (int kk = 0; kk < K; kk += 32) {
    gload16(Ag + kk, Asl);
    gload16(Ag + kk + 64 * K, Asl + 2048);
    gload16(Bg + kk, Bsl);
    gload16(Bg + kk + 64 * K, Bsl + 2048);
    __syncthreads();
    bf16x8 af[4], bf[4];
#pragma unroll
    for (int i = 0; i < 4; ++i)
      af[i] = *(const bf16x8*)&As[(wm + i * 16 + lr) * 32 + lq * 8];
#pragma unroll
    for (int j = 0; j < 4; ++j)
      bf[j] = *(const bf16x8*)&Bs[(wn + j * 16 + lr) * 32 + lq * 8];
#pragma unroll
    for (int i = 0; i < 4; ++i)
#pragma unroll
      for (int j = 0; j < 4; ++j)
        acc[i][j] = MFMA16(af[i], bf[j], acc[i][j]);
    __syncthreads();
  }

#pragma unroll
  for (int i = 0; i < 4; ++i) {
#pragma unroll
    for (int j = 0; j < 4; ++j) {
      int col = n0 + wn + j * 16 + lr;
      int tsel = col >> 10, rem = col & 1023;
      int h = rem >> 6, d = rem & 63;
      float bs = bias[col];
      int rowb = m0 + wm + i * 16 + lq * 4;
#pragma unroll
      for (int r = 0; r < 4; ++r) {
        int m = rowb + r;
        int b = m >> 11, sdx = m & 2047;
        __hip_bfloat16 v = __float2bfloat16(acc[i][j][r] + bs);
        long bh = (long)(b * 16 + h);
        if (tsel == 0) {
          Qo[(bh * 2048 + sdx) * 64 + d] = v;
        } else if (tsel == 1) {
          // K'[bh][kb][dh][dq][ki][di]
          Ko[(bh * 128 + (sdx >> 4)) * 1024 + (d >> 5) * 512 +
             ((d >> 3) & 3) * 128 + (sdx & 15) * 8 + (d & 7)] = v;
        } else {
          Vt[((bh * 128 + (sdx >> 4)) * 64 + d) * 16 + (sdx & 15)] = v;
        }
      }
    }
  }
}

// ---------------- fused attention v10b: zero-staging, 1 barrier/tile ----------------
// (v10 failed to compile: macro arg "2*kp" captured LOADKV's local pointer
// "kp". v10b = same design, macros replaced by array-reference lambdas --
// the pattern proven in r4-r9.)
// r9 post-mortem: 1 block/CU is register-bound (ctx in AGPRs; arch VGPR 96 +
// acc 64 ~= 160/wave) -- stop chasing occupancy, shorten the per-tile chain.
// v10: K retiled (see gemm1) -> QK frags load direct from global, coalesced.
// NO LDS staging at all: LDS = parity-dbuf psum (2x20 KB padded) + epilogue
// buf. ONE barrier per tile: write own partial -> BAR -> every wave reduces
// all 8 partials itself (no wave0/1 serialize, no second barrier, no vmcnt
// choreography). Parity dbuf makes 1-tile wave skew safe. Next-tile K/V
// loads issued right after QK consumes current frags (~600cy ahead of use).
// K/V served by per-XCD L2 (combo keeps 4 MB working set per XCD).
__global__ __launch_bounds__(512, 2) void attn_kernel(
    const __hip_bfloat16* __restrict__ Q,
    const __hip_bfloat16* __restrict__ K,
    const __hip_bfloat16* __restrict__ Vt,
    __hip_bfloat16* __restrict__ part) {
  __shared__ float psum[2][5120];                          // 40 KB [par][qt*2560+w*320+q*20+lq*4]
  __shared__ __align__(16) unsigned short epi[16 * 1024];  // 32 KB epilogue staging

  const int t = threadIdx.x, lane = t & 63, wv = t >> 6;
  const int lr = lane & 15, lq = lane >> 4;
  const int h0 = wv * 2;  // this wave's two heads
  const int combo = blockIdx.x & 7;
  const int b = combo & 1, chunk = combo >> 1;
  const int q0 = (blockIdx.x >> 3) * 32;
  const int kb0 = chunk * 32;
  const float c = 0.03125f * 1.44269504f;  // (1/sqrt(E)) * log2(e), E=1024
  const long bh16 = (long)(b * 16);
  const int poff = lr * 20 + lq * 4;       // padded psum offset (<=2-way banks)

  // Q fragments (B-operand of S^T): lane holds Q[q0+qt*16+lr][dh*32+lq*8..+8]
  bf16x8 qf[2][2][2];  // [hh][qt][dh]
#pragma unroll
  for (int hh = 0; hh < 2; ++hh)
#pragma unroll
    for (int qt = 0; qt < 2; ++qt)
#pragma unroll
      for (int dh = 0; dh < 2; ++dh)
        qf[hh][qt][dh] = *(const bf16x8*)(
            Q + ((bh16 + h0 + hh) * 2048 + q0 + qt * 16 + lr) * 64 + dh * 32 + lq * 8);

  bf16x8 kfA[2][2], kfB[2][2];  // [hh][dh], K frags (direct global)
  bf16x4 vgA[2][4], vgB[2][4];  // [hh][dt], V frags (direct global)

  // coalesced direct loads: K frag = 1 KB contiguous, V frag = 512 B contiguous
  auto loadKV = [&](bf16x8 (&KF)[2][2], bf16x4 (&VG)[2][4], int kb) {
#pragma unroll
    for (int hh = 0; hh < 2; ++hh) {
      const __hip_bfloat16* kptr =
          K + ((bh16 + h0 + hh) * 128 + kb) * 1024 + lq * 128 + lr * 8;
      KF[hh][0] = *(const bf16x8*)kptr;
      KF[hh][1] = *(const bf16x8*)(kptr + 512);
      const __hip_bfloat16* vptr =
          Vt + ((bh16 + h0 + hh) * 128 + kb) * 1024 + lr * 16 + lq * 4;
#pragma unroll
      for (int dt = 0; dt < 4; ++dt)
        VG[hh][dt] = *(const bf16x4*)(vptr + dt * 256);
    }
  };

  loadKV(kfA, vgA, kb0);

  f32x4 ctx[2][2][4] = {};  // [hh][qt][dt], lane: d = dt*16+lq*4+r, q = qt*16+lr

  auto body = [&](bf16x8 (&KF)[2][2], bf16x4 (&VG)[2][4],
                  bf16x8 (&KFN)[2][2], bf16x4 (&VGN)[2][4], int kt, int par) {
    // ---- S^T = K·Q^T: 2 heads x 2 q-tiles, K frags shared across qt ----
    f32x4 s[2][2];
    __builtin_amdgcn_s_setprio(1);
#pragma unroll
    for (int hh = 0; hh < 2; ++hh)
#pragma unroll
      for (int qt = 0; qt < 2; ++qt) {
        f32x4 a = {};
        a = MFMA16(KF[hh][0], qf[hh][qt][0], a);
        a = MFMA16(KF[hh][1], qf[hh][qt][1], a);
        s[hh][qt] = a;
      }
    __builtin_amdgcn_s_setprio(0);
    // ---- prefetch next tile's K/V into the other register set ----
    if (kt + 1 < 32) loadKV(KFN, VGN, kb0 + kt + 1);
    // ---- exp + per-wave 2-head partial sums (padded psum rows) ----
#pragma unroll
    for (int qt = 0; qt < 2; ++qt) {
      f32x4 pp;
#pragma unroll
      for (int r = 0; r < 4; ++r) {
        s[0][qt][r] = __builtin_amdgcn_exp2f(s[0][qt][r] * c);
        s[1][qt][r] = __builtin_amdgcn_exp2f(s[1][qt][r] * c);
        pp[r] = s[0][qt][r] + s[1][qt][r];
      }
      *(f32x4*)&psum[par][qt * 2560 + wv * 320 + poff] = pp;
    }
    block_sync_lds();  // single barrier per tile: partials visible
    // ---- every wave reduces all 8 partials itself (no serialize, no 2nd bar) ----
    f32x4 inv[2];
#pragma unroll
    for (int qt = 0; qt < 2; ++qt) {
      f32x4 tot = {};
#pragma unroll
      for (int w2 = 0; w2 < 8; ++w2)
        tot += *(const f32x4*)&psum[par][qt * 2560 + w2 * 320 + poff];
#pragma unroll
      for (int r = 0; r < 4; ++r) inv[qt][r] = __builtin_amdgcn_rcpf(tot[r]);
    }
    // ---- PV: p4 lane-local; V pre-loaded in registers ----
    __builtin_amdgcn_s_setprio(1);
#pragma unroll
    for (int hh = 0; hh < 2; ++hh)
#pragma unroll
      for (int qt = 0; qt < 2; ++qt) {
        bf16x4 p4;
#pragma unroll
        for (int r = 0; r < 4; ++r) p4[r] = (short)bf16bits(s[hh][qt][r] * inv[qt][r]);
#pragma unroll
        for (int dt = 0; dt < 4; ++dt)
          ctx[hh][qt][dt] = MFMA16K16(VG[hh][dt], p4, ctx[hh][qt][dt]);
      }
    __builtin_amdgcn_s_setprio(0);
    // no trailing barrier: parity-dbuf psum tolerates 1-tile wave skew.
  };

#pragma unroll 1
  for (int kp = 0; kp < 16; ++kp) {
    body(kfA, vgA, kfB, vgB, 2 * kp, 0);
    body(kfB, vgB, kfA, vgA, 2 * kp + 1, 1);
  }

  // ---- epilogue: per q-tile, ctx^T -> epi LDS -> coalesced store ----
  unsigned short* Pc = epi;
#pragma unroll
  for (int qt = 0; qt < 2; ++qt) {
    if (qt) block_sync_lds();  // pass-0 reads done before overwrite
#pragma unroll
    for (int hh = 0; hh < 2; ++hh) {
      const int h = h0 + hh;
#pragma unroll
      for (int dt = 0; dt < 4; ++dt) {
        bf16x4 pk;
#pragma unroll
        for (int r = 0; r < 4; ++r) pk[r] = (short)bf16bits(ctx[hh][qt][dt][r]);
        const int o = h * 128 + dt * 32 + lq * 8;  // byte off in hd-row (d=dt*16+lq*4+r)
        *(bf16x4*)((char*)Pc + lr * 2048 + (o ^ ((lr & 7) << 4))) = pk;
      }
    }
    block_sync_lds();
    unsigned short* gbase = (unsigned short*)part +
        ((long)(chunk * 4096 + b * 2048 + q0 + qt * 16)) * 1024;
#pragma unroll
    for (int j = 0; j < 4; ++j) {
      int gf = (j * 512 + t) * 8;  // flat over [16q][16h*64d]
      int q = gf >> 10, hd = gf & 1023;
      u16x8 v = *(const u16x8*)((char*)Pc + q * 2048 + ((hd * 2) ^ ((q & 7) << 4)));
      *(u16x8*)&gbase[gf] = v;
    }
  }
}

// ---------------- reduce 4 bf16 chunk partials + cast to bf16 ----------------
__global__ void reduce_cast_kernel(const unsigned short* __restrict__ part,
                                   __hip_bfloat16* __restrict__ dst) {
  int i = blockIdx.x * blockDim.x + threadIdx.x;  // 1M threads, 4 elems each
  const long S4 = (long)4096 * 1024 / 4;          // ushort4 units per chunk
  const ushort4* p = (const ushort4*)part;
  float sx = 0.f, sy = 0.f, sz = 0.f, sw = 0.f;
#pragma unroll
  for (int c = 0; c < 4; ++c) {
    ushort4 v = p[i + c * S4];
    sx += bf2f(v.x); sy += bf2f(v.y); sz += bf2f(v.z); sw += bf2f(v.w);
  }
  ushort4 u;
  u.x = bf16bits(sx); u.y = bf16bits(sy); u.z = bf16bits(sz); u.w = bf16bits(sw);
  ((ushort4*)dst)[i] = u;
}

// ---------------- GEMM2: out = ctxb @ woutb^T + b_out (fp32 out) ----------------
__global__ __launch_bounds__(256) void gemm_out_kernel(
    const __hip_bfloat16* __restrict__ A,   // [4096][1024]
    const __hip_bfloat16* __restrict__ B,   // [1024][1024]
    const float* __restrict__ bias,
    float* __restrict__ out) {
  const int K = 1024;
  __shared__ __align__(16) __hip_bfloat16 As[128 * 32];
  __shared__ __align__(16) __hip_bfloat16 Bs[128 * 32];
  const int t = threadIdx.x;
  const int lane = t & 63, wv = t >> 6;
  const int wm = (wv >> 1) * 64, wn = (wv & 1) * 64;
  const int lr = lane & 15, lq = lane >> 4;
  const int m0 = blockIdx.y * 128, n0 = blockIdx.x * 128;

  f32x4 acc[4][4] = {};

  const int arow = t >> 2;
  const int acol = (t & 3) * 8;
  const __hip_bfloat16* Ag = A + (long)(m0 + arow) * K + acol;
  const __hip_bfloat16* Bg = B + (long)(n0 + arow) * K + acol;
  __hip_bfloat16* Asl = As + t * 8;
  __hip_bfloat16* Bsl = Bs + t * 8;

  for (int kk = 0; kk < K; kk += 32) {
    gload16(Ag + kk, Asl);
    gload16(Ag + kk + 64 * K, Asl + 2048);
    gload16(Bg + kk, Bsl);
    gload16(Bg + kk + 64 * K, Bsl + 2048);
    __syncthreads();
    bf16x8 af[4], bf[4];
#pragma unroll
    for (int i = 0; i < 4; ++i)
      af[i] = *(const bf16x8*)&As[(wm + i * 16 + lr) * 32 + lq * 8];
#pragma unroll
    for (int j = 0; j < 4; ++j)
      bf[j] = *(const bf16x8*)&Bs[(wn + j * 16 + lr) * 32 + lq * 8];
#pragma unroll
    for (int i = 0; i < 4; ++i)
#pragma unroll
      for (int j = 0; j < 4; ++j)
        acc[i][j] = MFMA16(af[i], bf[j], acc[i][j]);
    __syncthreads();
  }

#pragma unroll
  for (int i = 0; i < 4; ++i) {
#pragma unroll
    for (int j = 0; j < 4; ++j) {
      int col = n0 + wn + j * 16 + lr;
      float bs = bias[col];
      int rowb = m0 + wm + i * 16 + lq * 4;
#pragma unroll
      for (int r = 0; r < 4; ++r) {
        out[(long)(rowb + r) * 1024 + col] = acc[i][j][r] + bs;
      }
    }
  }
}

extern "C" void kernel_launch(void* const* d_in, const int* in_sizes, int n_in,
                              void* d_out, int out_size, void* d_ws, size_t ws_size,
                              hipStream_t stream) {
  const float* x     = (const float*)d_in[0];
  const float* w_qkv = (const float*)d_in[1];
  const float* b_qkv = (const float*)d_in[2];
  const float* w_out = (const float*)d_in[3];
  const float* b_out = (const float*)d_in[4];
  float* out = (float*)d_out;
  char* ws = (char*)d_ws;

  // workspace layout (80 MB total)
  __hip_bfloat16* xb    = (__hip_bfloat16*)(ws);                       // 8 MB
  __hip_bfloat16* wqkvb = (__hip_bfloat16*)(ws + (8ul << 20));         // 6 MB
  __hip_bfloat16* woutb = (__hip_bfloat16*)(ws + (14ul << 20));        // 2 MB
  __hip_bfloat16* Qb    = (__hip_bfloat16*)(ws + (16ul << 20));        // 8 MB
  __hip_bfloat16* Kb    = (__hip_bfloat16*)(ws + (24ul << 20));        // 8 MB
  __hip_bfloat16* Vtb   = (__hip_bfloat16*)(ws + (32ul << 20));        // 8 MB
  __hip_bfloat16* partb = (__hip_bfloat16*)(ws + (40ul << 20));        // 32 MB (4 bf16 chunks)
  __hip_bfloat16* ctxb  = (__hip_bfloat16*)(ws + (72ul << 20));        // 8 MB

  cast_kernel<<<4096, 256, 0, stream>>>(x, xb, 4194304 / 4);
  cast_kernel<<<3072, 256, 0, stream>>>(w_qkv, wqkvb, 3145728 / 4);
  cast_kernel<<<1024, 256, 0, stream>>>(w_out, woutb, 1048576 / 4);
  gemm_qkv_kernel<<<dim3(24, 32), 256, 0, stream>>>(xb, wqkvb, b_qkv, Qb, Kb, Vtb);
  attn_kernel<<<512, 512, 0, stream>>>(Qb, Kb, Vtb, partb);
  reduce_cast_kernel<<<4096, 256, 0, stream>>>((const unsigned short*)partb, ctxb);
  gemm_out_kernel<<<dim3(8, 32), 256, 0, stream>>>(ctxb, woutb, b_out, out);
}

// Round 13
// 272.069 us; speedup vs baseline: 1.0689x; 1.0689x over previous
//
#include <hip/hip_runtime.h>
#include <hip/hip_bf16.h>
#include <stdint.h>

typedef float  f32x4  __attribute__((ext_vector_type(4)));
typedef short  bf16x8 __attribute__((ext_vector_type(8)));
typedef short  bf16x4 __attribute__((ext_vector_type(4)));
typedef unsigned short u16x8 __attribute__((ext_vector_type(8)));

#define MFMA16(a, b, c) __builtin_amdgcn_mfma_f32_16x16x32_bf16((a), (b), (c), 0, 0, 0)

// 16x16x16 bf16 MFMA: A/B = 4 bf16/lane (k = (lane>>4)*4 + reg), C/D standard 16x16.
#if __has_builtin(__builtin_amdgcn_mfma_f32_16x16x16bf16_1k)
#define MFMA16K16(a, b, c) __builtin_amdgcn_mfma_f32_16x16x16bf16_1k((a), (b), (c), 0, 0, 0)
#else
__device__ __forceinline__ f32x4 mfma16k16_asm(bf16x4 a, bf16x4 b, f32x4 c) {
  f32x4 d;
  asm volatile("v_mfma_f32_16x16x16_bf16 %0, %1, %2, %3"
               : "=v"(d) : "v"(a), "v"(b), "v"(c));
  return d;
}
#define MFMA16K16(a, b, c) mfma16k16_asm((a), (b), (c))
#endif

__device__ __forceinline__ void gload16(const void* g, void* l) {
  __builtin_amdgcn_global_load_lds((const __attribute__((address_space(1))) void*)g,
                                   (__attribute__((address_space(3))) void*)l,
                                   16, 0, 0);
}

__device__ __forceinline__ unsigned short bf16bits(float f) {
  __hip_bfloat16 h = __float2bfloat16(f);
  return *(unsigned short*)&h;
}

__device__ __forceinline__ float bf2f(unsigned short u) {
  unsigned int x = ((unsigned int)u) << 16;
  return *(float*)&x;
}

// LDS-only barrier: drains DS ops, leaves VMEM (vmcnt) in flight.
__device__ __forceinline__ void block_sync_lds() {
  asm volatile("s_waitcnt lgkmcnt(0)" ::: "memory");
  __builtin_amdgcn_s_barrier();
  asm volatile("" ::: "memory");
}

// ---------------- fp32 -> bf16 cast, 4 elems/thread ----------------
__global__ void cast_kernel(const float* __restrict__ s, __hip_bfloat16* __restrict__ d, int n4) {
  int i = blockIdx.x * blockDim.x + threadIdx.x;
  if (i < n4) {
    float4 v = ((const float4*)s)[i];
    ushort4 u;
    u.x = bf16bits(v.x); u.y = bf16bits(v.y); u.z = bf16bits(v.z); u.w = bf16bits(v.w);
    ((ushort4*)d)[i] = u;
  }
}

// ---------------- GEMM1: qkv = xb @ wqkvb^T + b_qkv; scatter to Q,K',Vtile (bf16) ----------------
// V layout: Vt[bh][kb=s/16][d=64][ki=16]. K layout:
// K'[bh][kb][dh=d/32][dq=(d/8)%4][ki=s%16][di=d%8] -- the QK A-fragment
// (lane holds K[k=lr][d=lq*8..+8]) is a wave-contiguous 1 KB b128 load.
__global__ __launch_bounds__(256) void gemm_qkv_kernel(
    const __hip_bfloat16* __restrict__ A,
    const __hip_bfloat16* __restrict__ B,
    const float* __restrict__ bias,
    __hip_bfloat16* __restrict__ Qo,
    __hip_bfloat16* __restrict__ Ko,
    __hip_bfloat16* __restrict__ Vt) {
  const int K = 1024;
  __shared__ __align__(16) __hip_bfloat16 As[128 * 32];
  __shared__ __align__(16) __hip_bfloat16 Bs[128 * 32];
  const int t = threadIdx.x;
  const int lane = t & 63, wv = t >> 6;
  const int wm = (wv >> 1) * 64, wn = (wv & 1) * 64;
  const int lr = lane & 15, lq = lane >> 4;
  const int m0 = blockIdx.y * 128, n0 = blockIdx.x * 128;

  f32x4 acc[4][4] = {};

  const int arow = t >> 2;
  const int acol = (t & 3) * 8;
  const __hip_bfloat16* Ag = A + (long)(m0 + arow) * K + acol;
  const __hip_bfloat16* Bg = B + (long)(n0 + arow) * K + acol;
  __hip_bfloat16* Asl = As + t * 8;
  __hip_bfloat16* Bsl = Bs + t * 8;

  for (int kk = 0; kk < K; kk += 32) {
    gload16(Ag + kk, Asl);
    gload16(Ag + kk + 64 * K, Asl + 2048);
    gload16(Bg + kk, Bsl);
    gload16(Bg + kk + 64 * K, Bsl + 2048);
    __syncthreads();
    bf16x8 af[4], bf[4];
#pragma unroll
    for (int i = 0; i < 4; ++i)
      af[i] = *(const bf16x8*)&As[(wm + i * 16 + lr) * 32 + lq * 8];
#pragma unroll
    for (int j = 0; j < 4; ++j)
      bf[j] = *(const bf16x8*)&Bs[(wn + j * 16 + lr) * 32 + lq * 8];
#pragma unroll
    for (int i = 0; i < 4; ++i)
#pragma unroll
      for (int j = 0; j < 4; ++j)
        acc[i][j] = MFMA16(af[i], bf[j], acc[i][j]);
    __syncthreads();
  }

#pragma unroll
  for (int i = 0; i < 4; ++i) {
#pragma unroll
    for (int j = 0; j < 4; ++j) {
      int col = n0 + wn + j * 16 + lr;
      int tsel = col >> 10, rem = col & 1023;
      int h = rem >> 6, d = rem & 63;
      float bs = bias[col];
      int rowb = m0 + wm + i * 16 + lq * 4;
#pragma unroll
      for (int r = 0; r < 4; ++r) {
        int m = rowb + r;
        int b = m >> 11, sdx = m & 2047;
        __hip_bfloat16 v = __float2bfloat16(acc[i][j][r] + bs);
        long bh = (long)(b * 16 + h);
        if (tsel == 0) {
          Qo[(bh * 2048 + sdx) * 64 + d] = v;
        } else if (tsel == 1) {
          // K'[bh][kb][dh][dq][ki][di]
          Ko[(bh * 128 + (sdx >> 4)) * 1024 + (d >> 5) * 512 +
             ((d >> 3) & 3) * 128 + (sdx & 15) * 8 + (d & 7)] = v;
        } else {
          Vt[((bh * 128 + (sdx >> 4)) * 64 + d) * 16 + (sdx & 15)] = v;
        }
      }
    }
  }
}

// ---------------- fused attention v12 (resubmit): split-reduce + 1-tile pipeline ----------------
// r12 bench was an infra double-failure (no compile error, no counters);
// line-audit found no divergent barrier, no OOB, no pipeline race (partials
// read-before-BAR(t+1)/rewritten-after; inv region disjoint from partials;
// dataflow traced tt=0..31+tail). Resubmitting unchanged.
// r11 post-mortem: the all-wave redundant reduce was an 8x LDS broadcast
// (128 KB/tile, conflicts UP to 8.6M, VALU 33%). Also resolved: per-SIMD
// VGPR pool = 512; 172 regs/wave (108 arch + 64 AGPR) -> 2 waves/SIMD ->
// 22% occupancy is this design's structural ceiling. Optimize the chain.
// v12, still zero-staging and ONE barrier per tile:
//  - split reduce: each lane of each wave owns ONE (qt,q,k) cell (8 waves x
//    64 lanes = all 512 cells): 8 scalar reads + rcp + 1 write. 16->2 KB/wave.
//  - PV pipelined 1 tile behind: body t = QK(t), prefK(t+1), exp(t),
//    partial-write(t,par), BAR, publish inv(t), read inv(t-1), PV(t-1),
//    prefV(t+1). Parity-dbuf psum regions keep all RAW/WAR pairs >=1
//    barrier apart. LDS/tile 144 -> ~50 KB.
__global__ __launch_bounds__(512, 2) void attn_kernel(
    const __hip_bfloat16* __restrict__ Q,
    const __hip_bfloat16* __restrict__ K,
    const __hip_bfloat16* __restrict__ Vt,
    __hip_bfloat16* __restrict__ part) {
  // per parity: 8 waves x 640 (2qt x 16q x 20pad) partials + 640 inv
  __shared__ float psum[2][5760];                          // 45 KB
  __shared__ __align__(16) unsigned short epi[16 * 1024];  // 32 KB epilogue staging

  const int t = threadIdx.x, lane = t & 63, wv = t >> 6;
  const int lr = lane & 15, lq = lane >> 4;
  const int h0 = wv * 2;  // this wave's two heads
  const int combo = blockIdx.x & 7;
  const int b = combo & 1, chunk = combo >> 1;
  const int q0 = (blockIdx.x >> 3) * 32;
  const int kb0 = chunk * 32;
  const float c = 0.03125f * 1.44269504f;  // (1/sqrt(E)) * log2(e), E=1024
  const long bh16 = (long)(b * 16);
  const int poff = lr * 20 + lq * 4;  // padded consumer offset (<=2-way banks)
  // reduce-slice cell owned by this lane: (qt, q, k)
  const int roff = (lane >> 5) * 320 + (wv * 2 + ((lane >> 4) & 1)) * 20 + (lane & 15);

  // Q fragments (B-operand of S^T): lane holds Q[q0+qt*16+lr][dh*32+lq*8..+8]
  bf16x8 qf[2][2][2];  // [hh][qt][dh]
#pragma unroll
  for (int hh = 0; hh < 2; ++hh)
#pragma unroll
    for (int qt = 0; qt < 2; ++qt)
#pragma unroll
      for (int dh = 0; dh < 2; ++dh)
        qf[hh][qt][dh] = *(const bf16x8*)(
            Q + ((bh16 + h0 + hh) * 2048 + q0 + qt * 16 + lr) * 64 + dh * 32 + lq * 8);

  bf16x8 kfA[2][2], kfB[2][2];  // [hh][dh], K frags (direct global, 1 KB contig)
  bf16x4 vgA[2][4], vgB[2][4];  // [hh][dt], V frags (direct global, 512 B contig)

  auto loadK = [&](bf16x8 (&KF)[2][2], int kb) {
#pragma unroll
    for (int hh = 0; hh < 2; ++hh) {
      const __hip_bfloat16* kptr =
          K + ((bh16 + h0 + hh) * 128 + kb) * 1024 + lq * 128 + lr * 8;
      KF[hh][0] = *(const bf16x8*)kptr;
      KF[hh][1] = *(const bf16x8*)(kptr + 512);
    }
  };
  auto loadV = [&](bf16x4 (&VG)[2][4], int kb) {
#pragma unroll
    for (int hh = 0; hh < 2; ++hh) {
      const __hip_bfloat16* vptr =
          Vt + ((bh16 + h0 + hh) * 128 + kb) * 1024 + lr * 16 + lq * 4;
#pragma unroll
      for (int dt = 0; dt < 4; ++dt)
        VG[hh][dt] = *(const bf16x4*)(vptr + dt * 256);
    }
  };

  loadK(kfA, kb0);
  loadV(vgA, kb0);

  f32x4 ctx[2][2][4] = {};  // [hh][qt][dt], lane: d = dt*16+lq*4+r, q = qt*16+lr
  f32x4 sA[2][2], sB[2][2];

  // body t: Sc <- QK(t) (K frags KFc); prefetch K(t+1)->KFn; exp+partial(par);
  // BAR; publish inv(t); read inv(t-1) [par^1]; PV(t-1) with Sp/VGp;
  // prefetch V(t+1)->VGp (VGp's old tile was just consumed).
  auto body = [&](bf16x8 (&KFc)[2][2], bf16x8 (&KFn)[2][2],
                  f32x4 (&Sc)[2][2], f32x4 (&Sp)[2][2],
                  bf16x4 (&VGp)[2][4], int tt, int par) {
    __builtin_amdgcn_s_setprio(1);
#pragma unroll
    for (int hh = 0; hh < 2; ++hh)
#pragma unroll
      for (int qt = 0; qt < 2; ++qt) {
        f32x4 a = {};
        a = MFMA16(KFc[hh][0], qf[hh][qt][0], a);
        a = MFMA16(KFc[hh][1], qf[hh][qt][1], a);
        Sc[hh][qt] = a;
      }
    __builtin_amdgcn_s_setprio(0);
    if (tt + 1 < 32) loadK(KFn, kb0 + tt + 1);
    // exp + per-wave 2-head partial sums
#pragma unroll
    for (int qt = 0; qt < 2; ++qt) {
      f32x4 pp;
#pragma unroll
      for (int r = 0; r < 4; ++r) {
        Sc[0][qt][r] = __builtin_amdgcn_exp2f(Sc[0][qt][r] * c);
        Sc[1][qt][r] = __builtin_amdgcn_exp2f(Sc[1][qt][r] * c);
        pp[r] = Sc[0][qt][r] + Sc[1][qt][r];
      }
      *(f32x4*)&psum[par][wv * 640 + qt * 320 + poff] = pp;
    }
    block_sync_lds();  // the ONE barrier: partials(t) visible
    // split reduce: this lane's single cell over 8 wave-partials -> inv(t)
    {
      float tot = 0.f;
#pragma unroll
      for (int w2 = 0; w2 < 8; ++w2) tot += psum[par][w2 * 640 + roff];
      psum[par][5120 + roff] = __builtin_amdgcn_rcpf(tot);
    }
    // PV(t-1): inv(t-1) was published in the previous barrier interval
    if (tt > 0) {
      f32x4 inv0 = *(const f32x4*)&psum[par ^ 1][5120 + poff];
      f32x4 inv1 = *(const f32x4*)&psum[par ^ 1][5120 + 320 + poff];
      __builtin_amdgcn_s_setprio(1);
#pragma unroll
      for (int hh = 0; hh < 2; ++hh)
#pragma unroll
        for (int qt = 0; qt < 2; ++qt) {
          const f32x4 iv = qt ? inv1 : inv0;
          bf16x4 p4;
#pragma unroll
          for (int r = 0; r < 4; ++r) p4[r] = (short)bf16bits(Sp[hh][qt][r] * iv[r]);
#pragma unroll
          for (int dt = 0; dt < 4; ++dt)
            ctx[hh][qt][dt] = MFMA16K16(VGp[hh][dt], p4, ctx[hh][qt][dt]);
        }
      __builtin_amdgcn_s_setprio(0);
    }
    if (tt + 1 < 32) loadV(VGp, kb0 + tt + 1);  // VGp's old tile just consumed
  };

#pragma unroll 1
  for (int kp = 0; kp < 16; ++kp) {
    body(kfA, kfB, sA, sB, vgB, 2 * kp, 0);      // even: PV(odd t-1) uses sB/vgB
    body(kfB, kfA, sB, sA, vgA, 2 * kp + 1, 1);  // odd: PV(even t-1) uses sA/vgA
  }

  // tail: PV(31) -- inv(31) published in body 31 (par 1); one barrier to see it
  block_sync_lds();
  {
    f32x4 inv0 = *(const f32x4*)&psum[1][5120 + poff];
    f32x4 inv1 = *(const f32x4*)&psum[1][5120 + 320 + poff];
    __builtin_amdgcn_s_setprio(1);
#pragma unroll
    for (int hh = 0; hh < 2; ++hh)
#pragma unroll
      for (int qt = 0; qt < 2; ++qt) {
        const f32x4 iv = qt ? inv1 : inv0;
        bf16x4 p4;
#pragma unroll
        for (int r = 0; r < 4; ++r) p4[r] = (short)bf16bits(sB[hh][qt][r] * iv[r]);
#pragma unroll
        for (int dt = 0; dt < 4; ++dt)
          ctx[hh][qt][dt] = MFMA16K16(vgB[hh][dt], p4, ctx[hh][qt][dt]);
      }
    __builtin_amdgcn_s_setprio(0);
  }

  // ---- epilogue: per q-tile, ctx^T -> epi LDS -> coalesced store ----
  unsigned short* Pc = epi;
#pragma unroll
  for (int qt = 0; qt < 2; ++qt) {
    if (qt) block_sync_lds();  // pass-0 reads done before overwrite
#pragma unroll
    for (int hh = 0; hh < 2; ++hh) {
      const int h = h0 + hh;
#pragma unroll
      for (int dt = 0; dt < 4; ++dt) {
        bf16x4 pk;
#pragma unroll
        for (int r = 0; r < 4; ++r) pk[r] = (short)bf16bits(ctx[hh][qt][dt][r]);
        const int o = h * 128 + dt * 32 + lq * 8;  // byte off in hd-row (d=dt*16+lq*4+r)
        *(bf16x4*)((char*)Pc + lr * 2048 + (o ^ ((lr & 7) << 4))) = pk;
      }
    }
    block_sync_lds();
    unsigned short* gbase = (unsigned short*)part +
        ((long)(chunk * 4096 + b * 2048 + q0 + qt * 16)) * 1024;
#pragma unroll
    for (int j = 0; j < 4; ++j) {
      int gf = (j * 512 + t) * 8;  // flat over [16q][16h*64d]
      int q = gf >> 10, hd = gf & 1023;
      u16x8 v = *(const u16x8*)((char*)Pc + q * 2048 + ((hd * 2) ^ ((q & 7) << 4)));
      *(u16x8*)&gbase[gf] = v;
    }
  }
}

// ---------------- reduce 4 bf16 chunk partials + cast to bf16 ----------------
__global__ void reduce_cast_kernel(const unsigned short* __restrict__ part,
                                   __hip_bfloat16* __restrict__ dst) {
  int i = blockIdx.x * blockDim.x + threadIdx.x;  // 1M threads, 4 elems each
  const long S4 = (long)4096 * 1024 / 4;          // ushort4 units per chunk
  const ushort4* p = (const ushort4*)part;
  float sx = 0.f, sy = 0.f, sz = 0.f, sw = 0.f;
#pragma unroll
  for (int c = 0; c < 4; ++c) {
    ushort4 v = p[i + c * S4];
    sx += bf2f(v.x); sy += bf2f(v.y); sz += bf2f(v.z); sw += bf2f(v.w);
  }
  ushort4 u;
  u.x = bf16bits(sx); u.y = bf16bits(sy); u.z = bf16bits(sz); u.w = bf16bits(sw);
  ((ushort4*)dst)[i] = u;
}

// ---------------- GEMM2: out = ctxb @ woutb^T + b_out (fp32 out) ----------------
__global__ __launch_bounds__(256) void gemm_out_kernel(
    const __hip_bfloat16* __restrict__ A,   // [4096][1024]
    const __hip_bfloat16* __restrict__ B,   // [1024][1024]
    const float* __restrict__ bias,
    float* __restrict__ out) {
  const int K = 1024;
  __shared__ __align__(16) __hip_bfloat16 As[128 * 32];
  __shared__ __align__(16) __hip_bfloat16 Bs[128 * 32];
  const int t = threadIdx.x;
  const int lane = t & 63, wv = t >> 6;
  const int wm = (wv >> 1) * 64, wn = (wv & 1) * 64;
  const int lr = lane & 15, lq = lane >> 4;
  const int m0 = blockIdx.y * 128, n0 = blockIdx.x * 128;

  f32x4 acc[4][4] = {};

  const int arow = t >> 2;
  const int acol = (t & 3) * 8;
  const __hip_bfloat16* Ag = A + (long)(m0 + arow) * K + acol;
  const __hip_bfloat16* Bg = B + (long)(n0 + arow) * K + acol;
  __hip_bfloat16* Asl = As + t * 8;
  __hip_bfloat16* Bsl = Bs + t * 8;

  for (int kk = 0; kk < K; kk += 32) {
    gload16(Ag + kk, Asl);
    gload16(Ag + kk + 64 * K, Asl + 2048);
    gload16(Bg + kk, Bsl);
    gload16(Bg + kk + 64 * K, Bsl + 2048);
    __syncthreads();
    bf16x8 af[4], bf[4];
#pragma unroll
    for (int i = 0; i < 4; ++i)
      af[i] = *(const bf16x8*)&As[(wm + i * 16 + lr) * 32 + lq * 8];
#pragma unroll
    for (int j = 0; j < 4; ++j)
      bf[j] = *(const bf16x8*)&Bs[(wn + j * 16 + lr) * 32 + lq * 8];
#pragma unroll
    for (int i = 0; i < 4; ++i)
#pragma unroll
      for (int j = 0; j < 4; ++j)
        acc[i][j] = MFMA16(af[i], bf[j], acc[i][j]);
    __syncthreads();
  }

#pragma unroll
  for (int i = 0; i < 4; ++i) {
#pragma unroll
    for (int j = 0; j < 4; ++j) {
      int col = n0 + wn + j * 16 + lr;
      float bs = bias[col];
      int rowb = m0 + wm + i * 16 + lq * 4;
#pragma unroll
      for (int r = 0; r < 4; ++r) {
        out[(long)(rowb + r) * 1024 + col] = acc[i][j][r] + bs;
      }
    }
  }
}

extern "C" void kernel_launch(void* const* d_in, const int* in_sizes, int n_in,
                              void* d_out, int out_size, void* d_ws, size_t ws_size,
                              hipStream_t stream) {
  const float* x     = (const float*)d_in[0];
  const float* w_qkv = (const float*)d_in[1];
  const float* b_qkv = (const float*)d_in[2];
  const float* w_out = (const float*)d_in[3];
  const float* b_out = (const float*)d_in[4];
  float* out = (float*)d_out;
  char* ws = (char*)d_ws;

  // workspace layout (80 MB total)
  __hip_bfloat16* xb    = (__hip_bfloat16*)(ws);                       // 8 MB
  __hip_bfloat16* wqkvb = (__hip_bfloat16*)(ws + (8ul << 20));         // 6 MB
  __hip_bfloat16* woutb = (__hip_bfloat16*)(ws + (14ul << 20));        // 2 MB
  __hip_bfloat16* Qb    = (__hip_bfloat16*)(ws + (16ul << 20));        // 8 MB
  __hip_bfloat16* Kb    = (__hip_bfloat16*)(ws + (24ul << 20));        // 8 MB
  __hip_bfloat16* Vtb   = (__hip_bfloat16*)(ws + (32ul << 20));        // 8 MB
  __hip_bfloat16* partb = (__hip_bfloat16*)(ws + (40ul << 20));        // 32 MB (4 bf16 chunks)
  __hip_bfloat16* ctxb  = (__hip_bfloat16*)(ws + (72ul << 20));        // 8 MB

  cast_kernel<<<4096, 256, 0, stream>>>(x, xb, 4194304 / 4);
  cast_kernel<<<3072, 256, 0, stream>>>(w_qkv, wqkvb, 3145728 / 4);
  cast_kernel<<<1024, 256, 0, stream>>>(w_out, woutb, 1048576 / 4);
  gemm_qkv_kernel<<<dim3(24, 32), 256, 0, stream>>>(xb, wqkvb, b_qkv, Qb, Kb, Vtb);
  attn_kernel<<<512, 512, 0, stream>>>(Qb, Kb, Vtb, partb);
  reduce_cast_kernel<<<4096, 256, 0, stream>>>((const unsigned short*)partb, ctxb);
  gemm_out_kernel<<<dim3(8, 32), 256, 0, stream>>>(ctxb, woutb, b_out, out);
}